// Round 3
// baseline (462.557 us; speedup 1.0000x reference)
//
#include <hip/hip_runtime.h>

#define CI   128
#define TT   8192
#define CO   256
#define KW   9
#define NQ   5
#define PADL 4
#define KDIM (CI*KW)       // 1152
#define NSTEP 36           // K-steps (K=32) per q
#define NF (NQ*NSTEP)      // 180
#define BCO  128
#define BT   128
#define XROWS 136
#define XPITCH 136         // 272B rows = 17 x 16B granules (odd) -> octet-clean reads
#define WBUF_SHORTS (BCO*32)

typedef __attribute__((ext_vector_type(8))) short short8;
typedef __attribute__((ext_vector_type(4))) float float4v;
typedef __attribute__((address_space(1))) const unsigned int ga_u32;
typedef __attribute__((address_space(3))) unsigned int la_u32;

static __device__ __forceinline__ short f2bf(float f) {
  union { float f; unsigned u; } c; c.f = f;
  unsigned u = c.u;
  return (short)((u + 0x7FFFu + ((u >> 16) & 1u)) >> 16);  // RNE
}

static __device__ __forceinline__ float tanh_fast(float z) {
  float e = __expf(2.f * z);
  return (e - 1.f) / (e + 1.f);
}

static __device__ __forceinline__ void gload_lds16(const short* g, short* l) {
  __builtin_amdgcn_global_load_lds((ga_u32*)g, (la_u32*)l, 16, 0, 0);
}

// ---- kernel 1: conv_weights (CO,CI,KW,NQ) fp32 -> wT[q][co][k*128+ci] bf16 ----
__global__ void selfonn_wtrans(const float* __restrict__ w, short* __restrict__ wT, int n) {
  int o = blockIdx.x * 256 + threadIdx.x;
  if (o >= n) return;
  int ci = o & (CI - 1);
  int k  = (o >> 7) % KW;
  int co = (o / KDIM) & (CO - 1);
  int q  = o / (KDIM * CO);
  wT[o] = f2bf(w[((co * CI + ci) * KW + k) * NQ + q]);
}

// ---- kernel 2: fused implicit-GEMM conv + nonlinearities + weighted sum ----
__global__ __launch_bounds__(256, 2) void selfonn_main(
    const float* __restrict__ x, const short* __restrict__ wT,
    const float* __restrict__ probs, float* __restrict__ out) {

  __shared__ __align__(16) short xs[XROWS][XPITCH];
  __shared__ __align__(16) short ws[3][WBUF_SHORTS];   // 3 x 8KB, swizzled slot layout
  __shared__ float opw[BCO][NQ];

  const int tid  = threadIdx.x;
  const int lane = tid & 63;
  const int wid  = tid >> 6;
  const int wm   = wid >> 1;
  const int wn   = wid & 1;
  const int l15  = lane & 15;
  const int lg   = lane >> 4;
  const int b    = blockIdx.z;
  const int co0  = blockIdx.y * BCO;
  const int t0   = blockIdx.x * BT;

  // operator softmax -> LDS
  if (tid < BCO) {
    float p[NQ];
    float mx = -1e30f;
    #pragma unroll
    for (int j = 0; j < NQ; ++j) { p[j] = probs[(co0 + tid) * NQ + j]; mx = fmaxf(mx, p[j]); }
    float s = 0.f;
    #pragma unroll
    for (int j = 0; j < NQ; ++j) { p[j] = __expf(p[j] - mx); s += p[j]; }
    float inv = 1.0f / s;
    #pragma unroll
    for (int j = 0; j < NQ; ++j) opw[tid][j] = p[j] * inv;
  }

  // stage x tile once (t-transposed, bf16): xs[tl][ci] = x[b][ci][t0-4+tl]
  const float* xb = x + (size_t)b * CI * TT;
  #pragma unroll
  for (int it = 0; it < 17; ++it) {
    int cell = tid + it * 256;
    int ci = cell & (CI - 1);
    int tc = cell >> 7;
    int tg = t0 - PADL + tc * 4;
    float4v v = {0.f, 0.f, 0.f, 0.f};
    if (tg >= 0 && tg <= TT - 4)
      v = *(const float4v*)(xb + (size_t)ci * TT + tg);
    int tl = tc * 4;
    xs[tl + 0][ci] = f2bf(v[0]);
    xs[tl + 1][ci] = f2bf(v[1]);
    xs[tl + 2][ci] = f2bf(v[2]);
    xs[tl + 3][ci] = f2bf(v[3]);
  }

  // ---- staging address precompute (inverse-swizzled global source) ----
  // LDS granule G = r*256 + tid holds ws row co_l = G>>2, PHYS slot G&3.
  // logical slot = (s_phys - (co_l>>1)) & 3 = (G - (G>>3)) & 3.
  int soff[2];
  #pragma unroll
  for (int r = 0; r < 2; ++r) {
    int G = r * 256 + tid;
    int co_l = G >> 2;
    int lgs  = (G - (G >> 3)) & 3;
    soff[r] = co_l * KDIM + lgs * 8;       // shorts; + q*CO*KDIM + step*32 per stage
  }
  const int sdst0 = (wid * 64) * 8;        // shorts; HW adds lane*16B
  const int sdst1 = (256 + wid * 64) * 8;

  // ---- ds_read offset precompute ----
  // af: ws row co = wm*64+m*16+l15, phys slot = (lg + (l15>>1)) & 3
  int afo[4], bfo[4];
  #pragma unroll
  for (int m = 0; m < 4; ++m)
    afo[m] = (wm * 64 + m * 16 + l15) * 32 + (((lg + (l15 >> 1)) & 3) << 3);
  #pragma unroll
  for (int n = 0; n < 4; ++n)
    bfo[n] = (wn * 64 + n * 16 + l15) * XPITCH + (lg << 3);

  const short* wq0 = wT + (size_t)co0 * KDIM;

  float4v oacc[4][4];
  float4v acc[4][4];
  #pragma unroll
  for (int m = 0; m < 4; ++m)
    #pragma unroll
    for (int n = 0; n < 4; ++n) {
      oacc[m][n] = (float4v){0.f, 0.f, 0.f, 0.f};
      acc[m][n]  = (float4v){0.f, 0.f, 0.f, 0.f};
    }

  // prologue: stage fi=0 (q0,s0) -> buf0, fi=1 (q0,s1) -> buf1
  gload_lds16(wq0 + soff[0],      &ws[0][0] + sdst0);
  gload_lds16(wq0 + soff[1],      &ws[0][0] + sdst1);
  gload_lds16(wq0 + soff[0] + 32, &ws[1][0] + sdst0);
  gload_lds16(wq0 + soff[1] + 32, &ws[1][0] + sdst1);
  __syncthreads();   // drains everything incl. prologue stages

  int cb = 0, sb = 2;
  int s_step = 2, s_qoff = 0;   // stage cursor = fi+2
  int q = 0, step = 0;

  for (int fi = 0; fi < NF; ++fi) {
    if (fi + 2 < NF) {
      const short* wp = wq0 + s_qoff + s_step * 32;
      short* lb = &ws[sb][0];
      gload_lds16(wp + soff[0], lb + sdst0);
      gload_lds16(wp + soff[1], lb + sdst1);
      if (++s_step == NSTEP) { s_step = 0; s_qoff += CO * KDIM; }
      asm volatile("s_waitcnt vmcnt(4)" ::: "memory");   // stage(fi) retired; fi+1,fi+2 in flight
    } else if (fi + 2 == NF) {
      asm volatile("s_waitcnt vmcnt(2)" ::: "memory");
    } else {
      asm volatile("s_waitcnt vmcnt(0)" ::: "memory");
    }
    __builtin_amdgcn_s_barrier();              // A: buf[cb] ready for all waves
    __builtin_amdgcn_sched_barrier(0);

    const short* wb = &ws[cb][0];
    const int k   = step >> 2;
    const int ci0 = (step & 3) << 5;
    const int bsh = k * XPITCH + ci0;
    short8 af[4], bfv[4];
    #pragma unroll
    for (int m = 0; m < 4; ++m)
      af[m] = *(const short8*)(wb + afo[m]);
    #pragma unroll
    for (int n = 0; n < 4; ++n)
      bfv[n] = *(const short8*)(&xs[0][0] + bfo[n] + bsh);

    __builtin_amdgcn_s_setprio(1);
    #pragma unroll
    for (int m = 0; m < 4; ++m)
      #pragma unroll
      for (int n = 0; n < 4; ++n)
        acc[m][n] = __builtin_amdgcn_mfma_f32_16x16x32_bf16(af[m], bfv[n], acc[m][n], 0, 0, 0);
    __builtin_amdgcn_s_setprio(0);

    if (step == NSTEP - 1) {
      #define DO_EPI(FEXPR)                                            \
        _Pragma("unroll") for (int m = 0; m < 4; ++m) {                \
          _Pragma("unroll") for (int jj = 0; jj < 4; ++jj) {           \
            int co_l = wm * 64 + m * 16 + lg * 4 + jj;                 \
            float wqv = opw[co_l][q];                                  \
            _Pragma("unroll") for (int n = 0; n < 4; ++n) {            \
              float z = acc[m][n][jj];                                 \
              float f = (FEXPR);                                       \
              oacc[m][n][jj] += wqv * f;                               \
              acc[m][n][jj] = 0.f;                                     \
            }                                                          \
          }                                                            \
        }
      if (q == 0)      { DO_EPI(z) }
      else if (q == 1) { DO_EPI(__sinf(z)) }
      else if (q == 2) { DO_EPI(__cosf(z)) }
      else if (q == 3) { DO_EPI(tanh_fast(z)) }
      else             { DO_EPI(__expf(fminf(fmaxf(z, -8.f), 8.f))) }
      #undef DO_EPI
    }
    __builtin_amdgcn_s_barrier();              // B: all reads of buf[cb] done

    if (++step == NSTEP) { step = 0; ++q; }
    cb = (cb == 2) ? 0 : cb + 1;
    sb = (sb == 2) ? 0 : sb + 1;
  }

  // store (B, CO, T) fp32
  float* ob = out + (size_t)(b * CO + co0) * TT;
  #pragma unroll
  for (int m = 0; m < 4; ++m) {
    #pragma unroll
    for (int jj = 0; jj < 4; ++jj) {
      int co_l = wm * 64 + m * 16 + lg * 4 + jj;
      int tcol = t0 + wn * 64 + l15;
      float* orow = ob + (size_t)co_l * TT + tcol;
      #pragma unroll
      for (int n = 0; n < 4; ++n)
        orow[n * 16] = oacc[m][n][jj];
    }
  }
}

extern "C" void kernel_launch(void* const* d_in, const int* in_sizes, int n_in,
                              void* d_out, int out_size, void* d_ws, size_t ws_size,
                              hipStream_t stream) {
  const float* x     = (const float*)d_in[0];
  const float* w     = (const float*)d_in[1];
  const float* probs = (const float*)d_in[2];
  float* out = (float*)d_out;
  short* wT  = (short*)d_ws;   // NQ*CO*KDIM*2 = 2.95 MB

  int nw = NQ * CO * KDIM;
  selfonn_wtrans<<<dim3((nw + 255) / 256), 256, 0, stream>>>(w, wT, nw);

  dim3 grid(TT / BT, CO / BCO, 16);
  selfonn_main<<<grid, 256, 0, stream>>>(x, wT, probs, out);
}